// Round 17
// baseline (752.221 us; speedup 1.0000x reference)
//
#include <hip/hip_runtime.h>
#include <hip/hip_bf16.h>

typedef short bf16x8 __attribute__((ext_vector_type(8)));
typedef float f32x4 __attribute__((ext_vector_type(4)));
typedef unsigned short u16;
typedef unsigned int u32;

__device__ __forceinline__ u16 f2bf(float f) {
  unsigned u = __float_as_uint(f);
  u += 0x7FFFu + ((u >> 16) & 1u);
  return (u16)(u >> 16);
}

__device__ __forceinline__ void cp16(const u16* g, u16* l) {
  __builtin_amdgcn_global_load_lds((const __attribute__((address_space(1))) u32*)(const void*)g,
                                   (__attribute__((address_space(3))) u32*)(void*)l, 16, 0, 0);
}

// ---------------- prep: weights permute+cast ----------------
// qkv_w rows: o = h*96 + d*3 + t  (reference reshape (h,dh,3))
// permuted rows: o' = t*384 + h*32 + d
__global__ void prep_kernel(const float* __restrict__ qkv_w, const float* __restrict__ qkv_b,
                            const float* __restrict__ out_w,
                            u16* __restrict__ qkv_wp, float* __restrict__ qkv_bp,
                            u16* __restrict__ out_wb) {
  int stride = gridDim.x * blockDim.x;
  int tid0 = blockIdx.x * blockDim.x + threadIdx.x;
  for (int i = tid0; i < 1152 * 384; i += stride) {
    int op = i / 384, kk = i - op * 384;
    int t3 = op / 384, rem = op - t3 * 384;
    int h = rem >> 5, d = rem & 31;
    int o = h * 96 + d * 3 + t3;
    qkv_wp[i] = f2bf(qkv_w[o * 384 + kk]);
  }
  for (int i = tid0; i < 1152; i += stride) {
    int t3 = i / 384, rem = i - t3 * 384;
    int h = rem >> 5, d = rem & 31;
    qkv_bp[i] = qkv_b[h * 96 + d * 3 + t3];
  }
  for (int i = tid0; i < 384 * 384; i += stride) out_wb[i] = f2bf(out_w[i]);
}

// ---------------- precompute combined bias+mask: bm[w][h][49][64] f32, j-interleaved ----
// storage position j' = (j%16)*4 + j/16  -> lane lrow reads float4 {j=0*16+lrow..3*16+lrow}
// j in [49,64) = -1e30 (kills padded K columns in softmax, branch-free)
__global__ void bmask_kernel(const int* __restrict__ rp_index, const float* __restrict__ rp_table,
                             const float* __restrict__ mask, float* __restrict__ bm, int nW) {
  int id = blockIdx.x * blockDim.x + threadIdx.x;
  int total = nW * 12 * 49 * 64;
  if (id >= total) return;
  int jp = id & 63;
  int j = (jp & 3) * 16 + (jp >> 2);  // inverse of interleave
  int rest = id >> 6;                 // [w][h][i]
  int i = rest % 49;
  rest /= 49;
  int h = rest % 12;
  int w = rest / 12;
  float v;
  if (j < 49) {
    int ij = i * 49 + j;
    v = rp_table[rp_index[ij] * 12 + h] + mask[(size_t)w * 2401 + ij];
  } else {
    v = -1e30f;
  }
  bm[id] = v;
}

// ---------------- GEMM C = A @ B^T (+bias), 128x128 tile, BK=64 ----------------
// R9/R12 loop; single-buffer 32 KB LDS, (256,4) -> 4 blocks/CU.
// T2 XOR swizzle + T1 bijective XCD swizzle.
// MODE 1: A = x f32 [M][384], CAST FUSED into reg-staged A (2x float4 -> f2bf ->
//         ds_write_b128, same swizzled LDS layout); DENSE bf16 epilogue -> outQK[M][1152].
// MODE 2: A = [M][384] bf16 via global_load_lds; f32 epilogue (+bias) -> outF [M][384]
template <int MODE>
__global__ __launch_bounds__(256, 4) void gemm_bt(const float* __restrict__ Axf,
                                                  const u16* __restrict__ A,
                                                  const u16* __restrict__ Bm,
                                                  const float* __restrict__ bias,
                                                  u16* __restrict__ outQK,
                                                  float* __restrict__ outF, int K, int ntiles) {
  __shared__ u16 As[128 * 64], Bs[128 * 64];
  int nwg = gridDim.x;
  int bid0 = blockIdx.x;
  int bid = ((nwg & 7) == 0) ? ((bid0 & 7) * (nwg >> 3) + (bid0 >> 3)) : bid0;
  int bm = bid / ntiles, bn = bid - bm * ntiles;
  size_t mBase = (size_t)bm * 128;
  int nBase = bn * 128;
  int Ncols = ntiles * 128;
  int t = threadIdx.x, lane = t & 63, wid = t >> 6;
  int wm = (wid >> 1) * 64, wn = (wid & 1) * 64;
  int lrow = lane & 15, kg = lane >> 4;
  int srow = t >> 3;              // staging row within 32-row group
  int sc = (t & 7) ^ (srow & 7);  // pre-swizzled source chunk (16B units, 0..7)
  f32x4 acc[4][4] = {};

  const u16* Arow = A + mBase * K;
  const float* Axrow = Axf + mBase * K;
  const u16* Brow = Bm + (size_t)nBase * K;

  int nk = K / 64;
  for (int tk = 0; tk < nk; ++tk) {
    __syncthreads();  // previous iteration's LDS reads complete before overwrite
#pragma unroll
    for (int i = 0; i < 4; i++) {
      int row = srow + 32 * i;
      if (MODE == 1) {
        // fused f32->bf16 A staging (identical swizzled layout to the cp16 path)
        const float* src = Axrow + (size_t)row * K + tk * 64 + sc * 8;
        f32x4 a0 = *(const f32x4*)src;
        f32x4 a1 = *(const f32x4*)(src + 4);
        bf16x8 v;
        v[0] = (short)f2bf(a0[0]); v[1] = (short)f2bf(a0[1]);
        v[2] = (short)f2bf(a0[2]); v[3] = (short)f2bf(a0[3]);
        v[4] = (short)f2bf(a1[0]); v[5] = (short)f2bf(a1[1]);
        v[6] = (short)f2bf(a1[2]); v[7] = (short)f2bf(a1[3]);
        *(bf16x8*)&As[(t + 256 * i) * 8] = v;  // ds_write_b128
      } else {
        cp16(Arow + (size_t)row * K + tk * 64 + sc * 8, &As[(t + 256 * i) * 8]);
      }
      cp16(Brow + (size_t)row * K + tk * 64 + sc * 8, &Bs[(t + 256 * i) * 8]);
    }
    __syncthreads();  // stage landed (barrier drains vmcnt + lgkmcnt)
#pragma unroll
    for (int kk = 0; kk < 2; kk++) {
      bf16x8 af[4], bfr[4];
      int ck = ((kk << 2) | kg) ^ (lrow & 7);
#pragma unroll
      for (int mt = 0; mt < 4; mt++)
        af[mt] = *(const bf16x8*)(&As[(wm + mt * 16 + lrow) * 64 + ck * 8]);
#pragma unroll
      for (int nt = 0; nt < 4; nt++)
        bfr[nt] = *(const bf16x8*)(&Bs[(wn + nt * 16 + lrow) * 64 + ck * 8]);
#pragma unroll
      for (int mt = 0; mt < 4; mt++)
#pragma unroll
        for (int nt = 0; nt < 4; nt++)
          acc[mt][nt] = __builtin_amdgcn_mfma_f32_16x16x32_bf16(af[mt], bfr[nt], acc[mt][nt], 0, 0, 0);
    }
  }

#pragma unroll
  for (int mt = 0; mt < 4; mt++) {
#pragma unroll
    for (int nt = 0; nt < 4; nt++) {
      int col = nBase + wn + nt * 16 + lrow;
      float bv = bias[col];
#pragma unroll
      for (int r = 0; r < 4; r++) {
        int m = (int)mBase + wm + mt * 16 + kg * 4 + r;
        if (MODE == 1) {
          outQK[(size_t)m * Ncols + col] = f2bf(acc[mt][nt][r] + bv);
        } else {
          outF[(size_t)m * Ncols + col] = acc[mt][nt][r] + bv;
        }
      }
    }
  }
}

// ---------------- attention: 1 block per (window, hi); wave w -> head hi*4+w -------------
// (R16 structure, proven: 3x parallelism, one head per wave, 2 barriers/block, o_sh
// aliases vt, dense 256B-segment coop store.)
__global__ __launch_bounds__(256, 3) void attn_kernel(const u16* __restrict__ qkv,
                                                      const f32x4* __restrict__ bm,
                                                      u16* __restrict__ aout,
                                                      int nW, int swz) {
  __shared__ __align__(16) char smem[49152];
  int bid = blockIdx.x;
  int b, hi;
  if (swz) {
    // bijective decode keeping 8 distinct w=b%64 per XCD (bm L2-resident):
    // bid = (((g*3+hi)*8 + wlow)*8 + x) ; w = x*8+wlow ; b = g*64 + w
    int x = bid & 7;
    int idx = bid >> 3;
    int wlow = idx & 7;
    int rest = idx >> 3;
    int g = rest / 3;
    hi = rest - g * 3;
    b = g * 64 + x * 8 + wlow;
  } else {
    b = bid / 3;
    hi = bid - b * 3;
  }
  int t = threadIdx.x, lane = t & 63, wid = t >> 6;
  int lrow = lane & 15, kg = lane >> 4;
  u16* pw = (u16*)(smem + wid * 8192);          // per-wave P [64][64] swizzled
  u16* vw = (u16*)(smem + 32768 + wid * 4096);  // per-wave V^T [32][64] swizzled
  u16* o_sh = (u16*)(smem + 32768);             // [49][136] aliases vt region (13328 B)
  const float scale = 0.17677669529663687f;     // 32^-0.5
  int wmask = b % nW;
  int h = hi * 4 + wid;  // this wave's head
  bf16x8 zer = {0, 0, 0, 0, 0, 0, 0, 0};

  int nclamp[4];
#pragma unroll
  for (int mt = 0; mt < 4; mt++) {
    int n = mt * 16 + lrow;
    nclamp[mt] = (n < 49) ? n : 0;  // clamp pad rows to row 0: finite values, killed by bm
  }

  // Q/K fragments for this head
  bf16x8 qf[4], kf[4];
#pragma unroll
  for (int mt = 0; mt < 4; mt++) {
    const u16* base = qkv + (size_t)(b * 49 + nclamp[mt]) * 1152 + h * 32 + kg * 8;
    qf[mt] = *(const bf16x8*)base;
    kf[mt] = *(const bf16x8*)(base + 384);
  }
  // issue V reads early (64B-chunked, coalesced); latency hides under softmax VALU
  bf16x8 vreg[4];
#pragma unroll
  for (int c = 0; c < 4; c++) {
    int idx = c * 64 + lane;
    int j = idx >> 2, dc = idx & 3;
    vreg[c] = (j < 49)
                  ? *(const bf16x8*)(qkv + (size_t)(b * 49 + j) * 1152 + 768 + h * 32 + dc * 8)
                  : zer;
  }
  const f32x4* bmh4 = bm + ((size_t)wmask * 12 + h) * (49 * 16);
  // per-mt: QK mfma -> softmax -> P write (s live range = 16 VGPR)
#pragma unroll
  for (int mt = 0; mt < 4; mt++) {
    f32x4 s[4];
#pragma unroll
    for (int nt = 0; nt < 4; nt++) {
      f32x4 z = {0.f, 0.f, 0.f, 0.f};
      s[nt] = __builtin_amdgcn_mfma_f32_16x16x32_bf16(qf[mt], kf[nt], z, 0, 0, 0);
    }
#pragma unroll
    for (int r = 0; r < 4; r++) {
      int i = mt * 16 + kg * 4 + r;
      int irow = (i < 49) ? i : 48;  // rows i>=49 discarded; any finite bm row works
      f32x4 bv = bmh4[irow * 16 + lrow];
      float vals[4];
      float mx = -1e30f;
#pragma unroll
      for (int nt = 0; nt < 4; nt++) {
        float v = fmaf(s[nt][r], scale, bv[nt]);
        vals[nt] = v;
        mx = fmaxf(mx, v);
      }
#pragma unroll
      for (int off = 1; off < 16; off <<= 1) mx = fmaxf(mx, __shfl_xor(mx, off, 64));
      float sum = 0.f;
#pragma unroll
      for (int nt = 0; nt < 4; nt++) {
        float p = __expf(vals[nt] - mx);
        vals[nt] = p;
        sum += p;
      }
#pragma unroll
      for (int off = 1; off < 16; off <<= 1) sum += __shfl_xor(sum, off, 64);
      float inv = 1.0f / sum;
#pragma unroll
      for (int nt = 0; nt < 4; nt++) {
        int j = nt * 16 + lrow;
        int addr = ((i * 64 + j) * 2) ^ ((i & 7) << 4);
        *(u16*)((char*)pw + addr) = f2bf(vals[nt] * inv);
      }
    }
  }
  // scatter V^T into vw: v[j][d] at byte (d*128 + j*2) ^ ((d&7)<<4) ^ (((d>>3)&3)<<5)
#pragma unroll
  for (int c = 0; c < 4; c++) {
    int idx = c * 64 + lane;
    int j = idx >> 2, dc = idx & 3;
#pragma unroll
    for (int e = 0; e < 8; e++) {
      int ba = ((dc * 8 + e) * 128 + j * 2) ^ (e << 4) ^ (dc << 5);
      *(u16*)((char*)vw + ba) = (u16)vreg[c][e];  // zer for j>=49 (0*NaN guard)
    }
  }
  asm volatile("s_waitcnt lgkmcnt(0)" ::: "memory");
  // PV: O[i][d] = sum_j P[i][j] * V[j][d]
  f32x4 o[4][2];
#pragma unroll
  for (int mt = 0; mt < 4; mt++)
#pragma unroll
    for (int nt = 0; nt < 2; nt++) o[mt][nt] = (f32x4){0.f, 0.f, 0.f, 0.f};
#pragma unroll
  for (int kt = 0; kt < 2; kt++) {
    bf16x8 pf[4], vv[2];
#pragma unroll
    for (int mt = 0; mt < 4; mt++) {
      int i = mt * 16 + lrow;
      int j = kt * 32 + kg * 8;
      int addr = ((i * 64 + j) * 2) ^ ((i & 7) << 4);
      pf[mt] = *(const bf16x8*)((const char*)pw + addr);
    }
#pragma unroll
    for (int nt = 0; nt < 2; nt++) {
      int d = nt * 16 + lrow;
      int ba = (d * 128 + (kt * 32 + kg * 8) * 2) ^ ((d & 7) << 4) ^ (((d >> 3) & 3) << 5);
      vv[nt] = *(const bf16x8*)((const char*)vw + ba);
    }
#pragma unroll
    for (int mt = 0; mt < 4; mt++)
#pragma unroll
      for (int nt = 0; nt < 2; nt++)
        o[mt][nt] = __builtin_amdgcn_mfma_f32_16x16x32_bf16(pf[mt], vv[nt], o[mt][nt], 0, 0, 0);
  }
  __syncthreads();  // ALL waves done reading vw -> safe to alias o_sh over it
  // o -> o_sh[49][136]: col = wid*32 + d (4 waves pack this block's 128 output cols)
#pragma unroll
  for (int mt = 0; mt < 4; mt++)
#pragma unroll
    for (int nt = 0; nt < 2; nt++)
#pragma unroll
      for (int r = 0; r < 4; r++) {
        int i = mt * 16 + kg * 4 + r;
        if (i < 49) {
          int d = nt * 16 + lrow;
          o_sh[i * 136 + wid * 32 + d] = f2bf(o[mt][nt][r]);
        }
      }
  __syncthreads();  // o_sh complete
  // dense coop store: 49 rows x 256B (2 full lines/row) at cols [hi*128, hi*128+128)
  u16* ab = aout + (size_t)(b * 49) * 384 + hi * 128;
  for (int idx = t; idx < 49 * 16; idx += 256) {
    int row = idx >> 4, c = idx & 15;
    *(bf16x8*)(ab + row * 384 + c * 8) = *(const bf16x8*)(&o_sh[row * 136 + c * 8]);
  }
}

extern "C" void kernel_launch(void* const* d_in, const int* in_sizes, int n_in,
                              void* d_out, int out_size, void* d_ws, size_t ws_size,
                              hipStream_t stream) {
  const float* x = (const float*)d_in[0];
  const float* qkv_w = (const float*)d_in[1];
  const float* qkv_b = (const float*)d_in[2];
  const float* rp_table = (const float*)d_in[3];
  const float* out_w = (const float*)d_in[4];
  const float* out_b = (const float*)d_in[5];
  const int* rp_index = (const int*)d_in[6];
  const float* mask = (const float*)d_in[7];

  int Bwin = in_sizes[0] / (49 * 384);  // 4096
  int nW = in_sizes[7] / (49 * 49);     // 64
  int M = Bwin * 49;                    // 200704 (divisible by 128)

  char* ws = (char*)d_ws;
  u16* attn_out = (u16*)(ws);                // 154,140,672 B : [M][384] bf16
  u16* qkvbuf = (u16*)(ws + 154140672);      // 462,422,016 B : [M][1152] bf16 dense
  u16* qkv_wp = (u16*)(ws + 616562688);      // 884,736 B
  float* qkv_bp = (float*)(ws + 617447424);  // 4,608 B
  u16* out_wb = (u16*)(ws + 617452032);      // 294,912 B
  float* bmbuf = (float*)(ws + 617746944);   // nW*12*49*64*4 = 9,633,792 B

  prep_kernel<<<1184, 256, 0, stream>>>(qkv_w, qkv_b, out_w, qkv_wp, qkv_bp, out_wb);
  int bmtotal = nW * 12 * 49 * 64;
  bmask_kernel<<<(bmtotal + 255) / 256, 256, 0, stream>>>(rp_index, rp_table, mask, bmbuf, nW);
  gemm_bt<1><<<(M / 128) * 9, 256, 0, stream>>>(x, nullptr, qkv_wp, qkv_bp, qkvbuf, nullptr,
                                                384, 9);
  int swz = (nW == 64 && (Bwin & 63) == 0) ? 1 : 0;
  attn_kernel<<<Bwin * 3, 256, 0, stream>>>(qkvbuf, (const f32x4*)bmbuf, attn_out, nW, swz);
  gemm_bt<2><<<(M / 128) * 3, 256, 0, stream>>>(nullptr, attn_out, out_wb, out_b, nullptr,
                                                (float*)d_out, 384, 3);
}

// Round 18
// 683.264 us; speedup vs baseline: 1.1009x; 1.1009x over previous
//
#include <hip/hip_runtime.h>
#include <hip/hip_bf16.h>

typedef short bf16x8 __attribute__((ext_vector_type(8)));
typedef float f32x4 __attribute__((ext_vector_type(4)));
typedef unsigned short u16;
typedef unsigned int u32;

__device__ __forceinline__ u16 f2bf(float f) {
  unsigned u = __float_as_uint(f);
  u += 0x7FFFu + ((u >> 16) & 1u);
  return (u16)(u >> 16);
}

__device__ __forceinline__ void cp16(const u16* g, u16* l) {
  __builtin_amdgcn_global_load_lds((const __attribute__((address_space(1))) u32*)(const void*)g,
                                   (__attribute__((address_space(3))) u32*)(void*)l, 16, 0, 0);
}

// ---------------- prep: weights permute+cast ----------------
// qkv_w rows: o = h*96 + d*3 + t  (reference reshape (h,dh,3))
// permuted rows: o' = t*384 + h*32 + d
__global__ void prep_kernel(const float* __restrict__ qkv_w, const float* __restrict__ qkv_b,
                            const float* __restrict__ out_w,
                            u16* __restrict__ qkv_wp, float* __restrict__ qkv_bp,
                            u16* __restrict__ out_wb) {
  int stride = gridDim.x * blockDim.x;
  int tid0 = blockIdx.x * blockDim.x + threadIdx.x;
  for (int i = tid0; i < 1152 * 384; i += stride) {
    int op = i / 384, kk = i - op * 384;
    int t3 = op / 384, rem = op - t3 * 384;
    int h = rem >> 5, d = rem & 31;
    int o = h * 96 + d * 3 + t3;
    qkv_wp[i] = f2bf(qkv_w[o * 384 + kk]);
  }
  for (int i = tid0; i < 1152; i += stride) {
    int t3 = i / 384, rem = i - t3 * 384;
    int h = rem >> 5, d = rem & 31;
    qkv_bp[i] = qkv_b[h * 96 + d * 3 + t3];
  }
  for (int i = tid0; i < 384 * 384; i += stride) out_wb[i] = f2bf(out_w[i]);
}

// ---------------- precompute combined bias+mask: bm[w][h][49][64] f32, j-interleaved ----
// storage position j' = (j%16)*4 + j/16  -> lane lrow reads float4 {j=0*16+lrow..3*16+lrow}
// j in [49,64) = -1e30 (kills padded K columns in softmax, branch-free)
__global__ void bmask_kernel(const int* __restrict__ rp_index, const float* __restrict__ rp_table,
                             const float* __restrict__ mask, float* __restrict__ bm, int nW) {
  int id = blockIdx.x * blockDim.x + threadIdx.x;
  int total = nW * 12 * 49 * 64;
  if (id >= total) return;
  int jp = id & 63;
  int j = (jp & 3) * 16 + (jp >> 2);  // inverse of interleave
  int rest = id >> 6;                 // [w][h][i]
  int i = rest % 49;
  rest /= 49;
  int h = rest % 12;
  int w = rest / 12;
  float v;
  if (j < 49) {
    int ij = i * 49 + j;
    v = rp_table[rp_index[ij] * 12 + h] + mask[(size_t)w * 2401 + ij];
  } else {
    v = -1e30f;
  }
  bm[id] = v;
}

// ---------------- GEMM C = A @ B^T (+bias), 128x128 tile, BK=64 ----------------
// R16 loop + T14 issue-early/write-late cast fusion (MODE 1):
//   per K-step: cvt+ds_write A[tk] from regs (no wait) | cp16 B[tk] | issue f32 loads
//   A[tk+1] (async; drains at the same barrier as B -> latencies overlap) | barrier | MFMA.
// Single-buffer 32 KB LDS. T2 XOR swizzle + T1 bijective XCD swizzle.
// MODE 1 (MINW=3, ~160-reg class incl. 32 Ar): A = x f32; DENSE bf16 -> outQK[M][1152].
// MODE 2 (MINW=4): A = [M][384] bf16 via cp16; f32 epilogue (+bias) -> outF [M][384]
template <int MODE, int MINW>
__global__ __launch_bounds__(256, MINW) void gemm_bt(const float* __restrict__ Axf,
                                                     const u16* __restrict__ A,
                                                     const u16* __restrict__ Bm,
                                                     const float* __restrict__ bias,
                                                     u16* __restrict__ outQK,
                                                     float* __restrict__ outF, int K, int ntiles) {
  __shared__ u16 As[128 * 64], Bs[128 * 64];
  int nwg = gridDim.x;
  int bid0 = blockIdx.x;
  int bid = ((nwg & 7) == 0) ? ((bid0 & 7) * (nwg >> 3) + (bid0 >> 3)) : bid0;
  int bm = bid / ntiles, bn = bid - bm * ntiles;
  size_t mBase = (size_t)bm * 128;
  int nBase = bn * 128;
  int Ncols = ntiles * 128;
  int t = threadIdx.x, lane = t & 63, wid = t >> 6;
  int wm = (wid >> 1) * 64, wn = (wid & 1) * 64;
  int lrow = lane & 15, kg = lane >> 4;
  int srow = t >> 3;              // staging row within 32-row group
  int sc = (t & 7) ^ (srow & 7);  // pre-swizzled source chunk (16B units, 0..7)
  f32x4 acc[4][4] = {};

  const u16* Arow = A + mBase * K;
  const float* Axrow = Axf + mBase * K;
  const u16* Brow = Bm + (size_t)nBase * K;

  f32x4 Ar[8];  // next-tile A f32 prefetch (statically indexed; 32 VGPR)
#define LOADA(tk)                                                              \
  {                                                                            \
    _Pragma("unroll") for (int i = 0; i < 4; i++) {                            \
      const float* s = Axrow + (size_t)(srow + 32 * i) * K + (tk) * 64 + sc * 8; \
      Ar[2 * i] = *(const f32x4*)s;                                            \
      Ar[2 * i + 1] = *(const f32x4*)(s + 4);                                  \
    }                                                                          \
  }

  if (MODE == 1) LOADA(0);
  int nk = K / 64;
  for (int tk = 0; tk < nk; ++tk) {
    __syncthreads();  // previous iteration's LDS reads done (and drains prologue loads)
    if (MODE == 1) {
      // cvt+write A[tk] from already-resident regs (no memory wait)
#pragma unroll
      for (int i = 0; i < 4; i++) {
        f32x4 a0 = Ar[2 * i], a1 = Ar[2 * i + 1];
        bf16x8 v;
        v[0] = (short)f2bf(a0[0]); v[1] = (short)f2bf(a0[1]);
        v[2] = (short)f2bf(a0[2]); v[3] = (short)f2bf(a0[3]);
        v[4] = (short)f2bf(a1[0]); v[5] = (short)f2bf(a1[1]);
        v[6] = (short)f2bf(a1[2]); v[7] = (short)f2bf(a1[3]);
        *(bf16x8*)&As[(t + 256 * i) * 8] = v;  // ds_write_b128
      }
    } else {
#pragma unroll
      for (int i = 0; i < 4; i++) {
        int row = srow + 32 * i;
        cp16(Arow + (size_t)row * K + tk * 64 + sc * 8, &As[(t + 256 * i) * 8]);
      }
    }
#pragma unroll
    for (int i = 0; i < 4; i++) {
      int row = srow + 32 * i;
      cp16(Brow + (size_t)row * K + tk * 64 + sc * 8, &Bs[(t + 256 * i) * 8]);
    }
    if (MODE == 1 && tk + 1 < nk) LOADA(tk + 1);  // async; overlaps B's cp16 latency
    __syncthreads();  // stage landed (barrier drains vmcnt + lgkmcnt)
#pragma unroll
    for (int kk = 0; kk < 2; kk++) {
      bf16x8 af[4], bfr[4];
      int ck = ((kk << 2) | kg) ^ (lrow & 7);
#pragma unroll
      for (int mt = 0; mt < 4; mt++)
        af[mt] = *(const bf16x8*)(&As[(wm + mt * 16 + lrow) * 64 + ck * 8]);
#pragma unroll
      for (int nt = 0; nt < 4; nt++)
        bfr[nt] = *(const bf16x8*)(&Bs[(wn + nt * 16 + lrow) * 64 + ck * 8]);
#pragma unroll
      for (int mt = 0; mt < 4; mt++)
#pragma unroll
        for (int nt = 0; nt < 4; nt++)
          acc[mt][nt] = __builtin_amdgcn_mfma_f32_16x16x32_bf16(af[mt], bfr[nt], acc[mt][nt], 0, 0, 0);
    }
  }
#undef LOADA

#pragma unroll
  for (int mt = 0; mt < 4; mt++) {
#pragma unroll
    for (int nt = 0; nt < 4; nt++) {
      int col = nBase + wn + nt * 16 + lrow;
      float bv = bias[col];
#pragma unroll
      for (int r = 0; r < 4; r++) {
        int m = (int)mBase + wm + mt * 16 + kg * 4 + r;
        if (MODE == 1) {
          outQK[(size_t)m * Ncols + col] = f2bf(acc[mt][nt][r] + bv);
        } else {
          outF[(size_t)m * Ncols + col] = acc[mt][nt][r] + bv;
        }
      }
    }
  }
}

// ---------------- attention: 1 block per (window, hi); wave w -> head hi*4+w -------------
// (R16 structure, proven: 3x parallelism, one head per wave, 2 barriers/block, o_sh
// aliases vt, dense 256B-segment coop store.)
__global__ __launch_bounds__(256, 3) void attn_kernel(const u16* __restrict__ qkv,
                                                      const f32x4* __restrict__ bm,
                                                      u16* __restrict__ aout,
                                                      int nW, int swz) {
  __shared__ __align__(16) char smem[49152];
  int bid = blockIdx.x;
  int b, hi;
  if (swz) {
    // bijective decode keeping 8 distinct w=b%64 per XCD (bm L2-resident):
    // bid = (((g*3+hi)*8 + wlow)*8 + x) ; w = x*8+wlow ; b = g*64 + w
    int x = bid & 7;
    int idx = bid >> 3;
    int wlow = idx & 7;
    int rest = idx >> 3;
    int g = rest / 3;
    hi = rest - g * 3;
    b = g * 64 + x * 8 + wlow;
  } else {
    b = bid / 3;
    hi = bid - b * 3;
  }
  int t = threadIdx.x, lane = t & 63, wid = t >> 6;
  int lrow = lane & 15, kg = lane >> 4;
  u16* pw = (u16*)(smem + wid * 8192);          // per-wave P [64][64] swizzled
  u16* vw = (u16*)(smem + 32768 + wid * 4096);  // per-wave V^T [32][64] swizzled
  u16* o_sh = (u16*)(smem + 32768);             // [49][136] aliases vt region (13328 B)
  const float scale = 0.17677669529663687f;     // 32^-0.5
  int wmask = b % nW;
  int h = hi * 4 + wid;  // this wave's head
  bf16x8 zer = {0, 0, 0, 0, 0, 0, 0, 0};

  int nclamp[4];
#pragma unroll
  for (int mt = 0; mt < 4; mt++) {
    int n = mt * 16 + lrow;
    nclamp[mt] = (n < 49) ? n : 0;  // clamp pad rows to row 0: finite values, killed by bm
  }

  // Q/K fragments for this head
  bf16x8 qf[4], kf[4];
#pragma unroll
  for (int mt = 0; mt < 4; mt++) {
    const u16* base = qkv + (size_t)(b * 49 + nclamp[mt]) * 1152 + h * 32 + kg * 8;
    qf[mt] = *(const bf16x8*)base;
    kf[mt] = *(const bf16x8*)(base + 384);
  }
  // issue V reads early (64B-chunked, coalesced); latency hides under softmax VALU
  bf16x8 vreg[4];
#pragma unroll
  for (int c = 0; c < 4; c++) {
    int idx = c * 64 + lane;
    int j = idx >> 2, dc = idx & 3;
    vreg[c] = (j < 49)
                  ? *(const bf16x8*)(qkv + (size_t)(b * 49 + j) * 1152 + 768 + h * 32 + dc * 8)
                  : zer;
  }
  const f32x4* bmh4 = bm + ((size_t)wmask * 12 + h) * (49 * 16);
  // per-mt: QK mfma -> softmax -> P write (s live range = 16 VGPR)
#pragma unroll
  for (int mt = 0; mt < 4; mt++) {
    f32x4 s[4];
#pragma unroll
    for (int nt = 0; nt < 4; nt++) {
      f32x4 z = {0.f, 0.f, 0.f, 0.f};
      s[nt] = __builtin_amdgcn_mfma_f32_16x16x32_bf16(qf[mt], kf[nt], z, 0, 0, 0);
    }
#pragma unroll
    for (int r = 0; r < 4; r++) {
      int i = mt * 16 + kg * 4 + r;
      int irow = (i < 49) ? i : 48;  // rows i>=49 discarded; any finite bm row works
      f32x4 bv = bmh4[irow * 16 + lrow];
      float vals[4];
      float mx = -1e30f;
#pragma unroll
      for (int nt = 0; nt < 4; nt++) {
        float v = fmaf(s[nt][r], scale, bv[nt]);
        vals[nt] = v;
        mx = fmaxf(mx, v);
      }
#pragma unroll
      for (int off = 1; off < 16; off <<= 1) mx = fmaxf(mx, __shfl_xor(mx, off, 64));
      float sum = 0.f;
#pragma unroll
      for (int nt = 0; nt < 4; nt++) {
        float p = __expf(vals[nt] - mx);
        vals[nt] = p;
        sum += p;
      }
#pragma unroll
      for (int off = 1; off < 16; off <<= 1) sum += __shfl_xor(sum, off, 64);
      float inv = 1.0f / sum;
#pragma unroll
      for (int nt = 0; nt < 4; nt++) {
        int j = nt * 16 + lrow;
        int addr = ((i * 64 + j) * 2) ^ ((i & 7) << 4);
        *(u16*)((char*)pw + addr) = f2bf(vals[nt] * inv);
      }
    }
  }
  // scatter V^T into vw: v[j][d] at byte (d*128 + j*2) ^ ((d&7)<<4) ^ (((d>>3)&3)<<5)
#pragma unroll
  for (int c = 0; c < 4; c++) {
    int idx = c * 64 + lane;
    int j = idx >> 2, dc = idx & 3;
#pragma unroll
    for (int e = 0; e < 8; e++) {
      int ba = ((dc * 8 + e) * 128 + j * 2) ^ (e << 4) ^ (dc << 5);
      *(u16*)((char*)vw + ba) = (u16)vreg[c][e];  // zer for j>=49 (0*NaN guard)
    }
  }
  asm volatile("s_waitcnt lgkmcnt(0)" ::: "memory");
  // PV: O[i][d] = sum_j P[i][j] * V[j][d]
  f32x4 o[4][2];
#pragma unroll
  for (int mt = 0; mt < 4; mt++)
#pragma unroll
    for (int nt = 0; nt < 2; nt++) o[mt][nt] = (f32x4){0.f, 0.f, 0.f, 0.f};
#pragma unroll
  for (int kt = 0; kt < 2; kt++) {
    bf16x8 pf[4], vv[2];
#pragma unroll
    for (int mt = 0; mt < 4; mt++) {
      int i = mt * 16 + lrow;
      int j = kt * 32 + kg * 8;
      int addr = ((i * 64 + j) * 2) ^ ((i & 7) << 4);
      pf[mt] = *(const bf16x8*)((const char*)pw + addr);
    }
#pragma unroll
    for (int nt = 0; nt < 2; nt++) {
      int d = nt * 16 + lrow;
      int ba = (d * 128 + (kt * 32 + kg * 8) * 2) ^ ((d & 7) << 4) ^ (((d >> 3) & 3) << 5);
      vv[nt] = *(const bf16x8*)((const char*)vw + ba);
    }
#pragma unroll
    for (int mt = 0; mt < 4; mt++)
#pragma unroll
      for (int nt = 0; nt < 2; nt++)
        o[mt][nt] = __builtin_amdgcn_mfma_f32_16x16x32_bf16(pf[mt], vv[nt], o[mt][nt], 0, 0, 0);
  }
  __syncthreads();  // ALL waves done reading vw -> safe to alias o_sh over it
  // o -> o_sh[49][136]: col = wid*32 + d (4 waves pack this block's 128 output cols)
#pragma unroll
  for (int mt = 0; mt < 4; mt++)
#pragma unroll
    for (int nt = 0; nt < 2; nt++)
#pragma unroll
      for (int r = 0; r < 4; r++) {
        int i = mt * 16 + kg * 4 + r;
        if (i < 49) {
          int d = nt * 16 + lrow;
          o_sh[i * 136 + wid * 32 + d] = f2bf(o[mt][nt][r]);
        }
      }
  __syncthreads();  // o_sh complete
  // dense coop store: 49 rows x 256B (2 full lines/row) at cols [hi*128, hi*128+128)
  u16* ab = aout + (size_t)(b * 49) * 384 + hi * 128;
  for (int idx = t; idx < 49 * 16; idx += 256) {
    int row = idx >> 4, c = idx & 15;
    *(bf16x8*)(ab + row * 384 + c * 8) = *(const bf16x8*)(&o_sh[row * 136 + c * 8]);
  }
}

extern "C" void kernel_launch(void* const* d_in, const int* in_sizes, int n_in,
                              void* d_out, int out_size, void* d_ws, size_t ws_size,
                              hipStream_t stream) {
  const float* x = (const float*)d_in[0];
  const float* qkv_w = (const float*)d_in[1];
  const float* qkv_b = (const float*)d_in[2];
  const float* rp_table = (const float*)d_in[3];
  const float* out_w = (const float*)d_in[4];
  const float* out_b = (const float*)d_in[5];
  const int* rp_index = (const int*)d_in[6];
  const float* mask = (const float*)d_in[7];

  int Bwin = in_sizes[0] / (49 * 384);  // 4096
  int nW = in_sizes[7] / (49 * 49);     // 64
  int M = Bwin * 49;                    // 200704 (divisible by 128)

  char* ws = (char*)d_ws;
  u16* attn_out = (u16*)(ws);                // 154,140,672 B : [M][384] bf16
  u16* qkvbuf = (u16*)(ws + 154140672);      // 462,422,016 B : [M][1152] bf16 dense
  u16* qkv_wp = (u16*)(ws + 616562688);      // 884,736 B
  float* qkv_bp = (float*)(ws + 617447424);  // 4,608 B
  u16* out_wb = (u16*)(ws + 617452032);      // 294,912 B
  float* bmbuf = (float*)(ws + 617746944);   // nW*12*49*64*4 = 9,633,792 B

  prep_kernel<<<1184, 256, 0, stream>>>(qkv_w, qkv_b, out_w, qkv_wp, qkv_bp, out_wb);
  int bmtotal = nW * 12 * 49 * 64;
  bmask_kernel<<<(bmtotal + 255) / 256, 256, 0, stream>>>(rp_index, rp_table, mask, bmbuf, nW);
  gemm_bt<1, 3><<<(M / 128) * 9, 256, 0, stream>>>(x, nullptr, qkv_wp, qkv_bp, qkvbuf, nullptr,
                                                   384, 9);
  int swz = (nW == 64 && (Bwin & 63) == 0) ? 1 : 0;
  attn_kernel<<<Bwin * 3, 256, 0, stream>>>(qkvbuf, (const f32x4*)bmbuf, attn_out, nW, swz);
  gemm_bt<2, 4><<<(M / 128) * 3, 256, 0, stream>>>(nullptr, attn_out, out_wb, out_b, nullptr,
                                                   (float*)d_out, 384, 3);
}